// Round 8
// baseline (102.921 us; speedup 1.0000x reference)
//
#include <hip/hip_runtime.h>

// 8-qubit statevector sim, R8: MFMA reformulation.
// Ladder R0-R7: every shuffle-statevector variant (scalar/packed, DS/DPP/hybrid,
// 25%/100% occupancy, 36/100 VGPR, 32/24 gates) pinned at qsim ~38-48us ->
// architecture floor, not schedule floor. R8 uses the idle matrix pipe:
//   phi = Utilde * psi,  Utilde (256x256, weights-only) = the 24 masked gates
//   (layers 1-3, CNOTs deferred -- validated machinery), psi = encode+layer0
//   product state (validated R6 fold), measurement = signed sums with amp-bit
//   masks R = {80,40,20,10,88,44,22,11} (validated).
// Kernel A: build Utilde columns by evolving 256 basis states (16 blocks).
// Kernel B: per block 64 samples: encode->LDS(f16), GEMM vs Utilde^T (f16
//   16x16x32 MFMA, fp32 acc; A/B use identical per-lane k-indexing so the HW
//   k-permutation cancels), fused measurement epilogue.

typedef _Float16 f16;
typedef _Float16 h8_t __attribute__((ext_vector_type(8)));
typedef float f4_t __attribute__((ext_vector_type(4)));

#define NGATES 32

// ---------------- validated deferred-CNOT mask machinery ----------------
constexpr bool selon(int l, int d) {
    return (l == 0) ? (d == 0) : (((d + l - 1) & (l - 1)) == (l - 1));
}
constexpr int lm_of(int l, int q) {
    int m = 0;
    for (int d = 0; q + d <= 7; ++d)
        if ((l & d) == d) { int qq = q + d; if (qq <= 3) m |= 1 << (3 - qq); }
    return m;
}
constexpr int rm_of(int l, int q) {
    int m = 0;
    for (int d = 0; q + d <= 7; ++d)
        if ((l & d) == d) { int qq = q + d; if (qq >= 4) m |= 1 << (7 - qq); }
    return m;
}
constexpr int slm_of(int l, int q) {
    int m = 0;
    for (int d = 0; d <= q; ++d)
        if (selon(l, d)) { int k = q - d; if (k <= 3) m |= 1 << (3 - k); }
    return m;
}
constexpr int srm_of(int l, int q) {
    int m = 0;
    for (int d = 0; d <= q; ++d)
        if (selon(l, d)) { int k = q - d; if (k >= 4) m |= 1 << (7 - k); }
    return m;
}

__device__ __forceinline__ float xsgn(float f, unsigned m) {
    return __int_as_float(__float_as_int(f) ^ (int)m);
}

template<int C>
__device__ __forceinline__ int dppmov(int x) {
    return __builtin_amdgcn_update_dpp(x, x, C, 0xF, 0xF, false);
}
template<int M>
__device__ __forceinline__ float shx_dpp(float v) {
    int x = __float_as_int(v);
    if constexpr (M == 1)       { x = dppmov<0xB1>(x); }
    else if constexpr (M == 2)  { x = dppmov<0x4E>(x); }
    else if constexpr (M == 3)  { x = dppmov<0x1B>(x); }
    else if constexpr (M == 7)  { x = dppmov<0x141>(x); }
    else if constexpr (M == 8)  { x = dppmov<0x128>(x); }
    else                        { x = dppmov<0x140>(x); }  // 15
    return __int_as_float(x);
}
template<int M>
__device__ __forceinline__ float shx_ds(float v) {
    return __int_as_float(__builtin_amdgcn_ds_swizzle(__float_as_int(v), (M << 10) | 0x1F));
}
constexpr bool sgl(int M) {
    return M == 1 || M == 2 || M == 3 || M == 7 || M == 8 || M == 15;
}
template<int M>
__device__ __forceinline__ float shxm(float v) {
    if constexpr (sgl(M)) return shx_dpp<M>(v);
    else                  return shx_ds<M>(v);
}

template<int LM, int RM, int SLM, int SRM>
__device__ __forceinline__ void apply_gate(float ar[16], float ai[16], int lane,
                                           const float4 g)
{
    unsigned sm = 0;
    if constexpr (SLM != 0)
        sm = (unsigned)((__builtin_popcount(lane & SLM) & 1) << 31);
    const float c0r = g.x, c1i = g.w;
    const float c0i0 = xsgn(g.y, sm);
    const float c1r0 = xsgn(g.z, sm);
    const float c0i1 = xsgn(g.y, sm ^ 0x80000000u);
    const float c1r1 = xsgn(g.z, sm ^ 0x80000000u);

    float br[16], bi[16];
    #pragma unroll
    for (int r = 0; r < 16; ++r) {
        float pr = ar[r ^ RM], pi = ai[r ^ RM];
        if constexpr (LM != 0) { pr = shxm<LM>(pr); pi = shxm<LM>(pi); }
        br[r] = pr; bi[r] = pi;
    }
    #pragma unroll
    for (int r = 0; r < 16; ++r) {
        const bool c1 = (__builtin_popcount(r & SRM) & 1) != 0;
        const float c0i = c1 ? c0i1 : c0i0;
        const float c1r = c1 ? c1r1 : c1r0;
        const float nr = c0r*ar[r] - c0i*ai[r] + c1r*br[r] - c1i*bi[r];
        const float ni = c0r*ai[r] + c0i*ar[r] + c1r*bi[r] + c1i*br[r];
        ar[r] = nr; ai[r] = ni;
    }
}

#define GATE(L, Q) apply_gate<lm_of(L,Q), rm_of(L,Q), slm_of(L,Q), srm_of(L,Q)>( \
                       ar, ai, lane, gsh4[(L)*8+(Q)])
#define LAYER(L) GATE(L,0); GATE(L,1); GATE(L,2); GATE(L,3); \
                 GATE(L,4); GATE(L,5); GATE(L,6); GATE(L,7);

// fused U = RZ*RY*RX row0 (u11=conj(u00), u10=-conj(u01))
__device__ __forceinline__ float4 gate_row0(const float* w, int g) {
    float hx = 0.5f * w[g*3+0];
    float hy = 0.5f * w[g*3+1];
    float hz = 0.5f * w[g*3+2];
    float cx = cosf(hx), sx = sinf(hx);
    float cy = cosf(hy), sy = sinf(hy);
    float cz = cosf(hz), sz = sinf(hz);
    float m00r = cy*cx,  m00i =  sy*sx;
    float m01r = -sy*cx, m01i = -cy*sx;
    return make_float4(cz*m00r + sz*m00i,
                       cz*m00i - sz*m00r,
                       cz*m01r + sz*m01i,
                       cz*m01i - sz*m01r);
}

// ---------------- kernel A: build Utilde columns ----------------
// 16 blocks x 16 basis states. Evolve e_j by LAYER(1..3); write
// Bt[i][j] = Utilde[i][j] as f16 (row-major [i][256]).
__global__ __launch_bounds__(256, 4) void build_u(const float* __restrict__ w,
                                                  f16* __restrict__ bt_r,
                                                  f16* __restrict__ bt_i)
{
    __shared__ float4 gsh4[NGATES];
    const int tid = threadIdx.x;
    if (tid < NGATES) gsh4[tid] = gate_row0(w, tid);
    __syncthreads();

    const int lane = tid & 63;
    const int il   = lane & 15;
    const int j    = blockIdx.x * 16 + (tid >> 4);   // basis index 0..255

    float ar[16], ai[16];
    #pragma unroll
    for (int r = 0; r < 16; ++r) {
        ar[r] = (il == (j >> 4) && r == (j & 15)) ? 1.f : 0.f;
        ai[r] = 0.f;
    }
    LAYER(1)
    LAYER(2)
    LAYER(3)
    #pragma unroll
    for (int r = 0; r < 16; ++r) {
        const int i = il * 16 + r;
        bt_r[i * 256 + j] = (f16)ar[r];
        bt_i[i * 256 + j] = (f16)ai[r];
    }
}

// ---------------- kernel B: encode + GEMM + measurement ----------------
struct cpx { float r, i; };
__device__ __forceinline__ cpx cmul(cpx a, cpx b) {
    return { a.r*b.r - a.i*b.i, a.r*b.i + a.i*b.r };
}

__device__ __forceinline__ f4_t mfma16(h8_t a, h8_t b, f4_t c) {
    return __builtin_amdgcn_mfma_f32_16x16x32_f16(a, b, c, 0, 0, 0);
}

__global__ __launch_bounds__(256, 1) void qsim_mm(const float* __restrict__ x,
                                                  const float* __restrict__ w,
                                                  const f16* __restrict__ bt_r,
                                                  const f16* __restrict__ bt_i,
                                                  float* __restrict__ out)
{
    __shared__ f16  As_r[64][264], As_i[64][264];   // psi, f16, padded
    __shared__ f16  BL_r[256][40], BL_i[256][40];   // Utilde k-slab, padded
    __shared__ float4 g0[8];
    __shared__ float zbuf[4][64][8];

    const int tid  = threadIdx.x;
    const int lane = tid & 63;
    const int wv   = tid >> 6;          // wave 0..3 -> ntiles wv*4..wv*4+3
    const int lg   = (lane >> 4) & 3;   // k-group / row-group
    const int col  = lane & 15;

    if (tid < 8) g0[tid] = gate_row0(w, tid);
    __syncthreads();

    // ---- encode: psi = prod_q (alpha,beta), layer-0 folded (validated R6) ----
    {
        const int sl = tid >> 2, pt = tid & 3;      // 64 samples x 4 threads
        const float4* xp = (const float4*)(x + (blockIdx.x * 64 + sl) * 8);
        float4 xa = xp[0], xb = xp[1];
        float xs[8] = {xa.x, xa.y, xa.z, xa.w, xb.x, xb.y, xb.z, xb.w};
        cpx f0[8], f1[8];
        #pragma unroll
        for (int q = 0; q < 8; ++q) {
            float c, s;
            __sincosf(0.5f * xs[q], &s, &c);
            const float4 g = g0[q];
            f0[q] = { g.x*c + g.z*s, g.y*c + g.w*s };   // alpha
            f1[q] = { g.x*s - g.z*c, g.w*c - g.y*s };   // beta
        }
        cpx t01[4], t23[4], t45[4], t67[4];
        #pragma unroll
        for (int a = 0; a < 2; ++a)
            #pragma unroll
            for (int b = 0; b < 2; ++b) {
                t01[a*2+b] = cmul(a ? f1[0] : f0[0], b ? f1[1] : f0[1]);
                t23[a*2+b] = cmul(a ? f1[2] : f0[2], b ? f1[3] : f0[3]);
                t45[a*2+b] = cmul(a ? f1[4] : f0[4], b ? f1[5] : f0[5]);
                t67[a*2+b] = cmul(a ? f1[6] : f0[6], b ? f1[7] : f0[7]);
            }
        cpx P03[16], P47[16];
        #pragma unroll
        for (int h = 0; h < 16; ++h) {
            P03[h] = cmul(t01[h >> 2], t23[h & 3]);
            P47[h] = cmul(t45[h >> 2], t67[h & 3]);
        }
        #pragma unroll
        for (int c8 = 0; c8 < 8; ++c8) {            // 64 entries in 8-chunks
            const int j0 = pt * 64 + c8 * 8;
            const int hi = j0 >> 4, lo0 = j0 & 15;
            h8_t vr, vi;
            #pragma unroll
            for (int e = 0; e < 8; ++e) {
                cpx cc = cmul(P03[hi], P47[lo0 + e]);
                vr[e] = (f16)cc.r; vi[e] = (f16)cc.i;
            }
            *(h8_t*)&As_r[sl][j0] = vr;
            *(h8_t*)&As_i[sl][j0] = vi;
        }
    }
    // ---- stage k-slab 0 of Utilde^T ----
    {
        const f16* sr = bt_r + tid * 256;
        const f16* si = bt_i + tid * 256;
        #pragma unroll
        for (int c = 0; c < 4; ++c) {
            *(h8_t*)&BL_r[tid][c*8] = *(const h8_t*)(sr + c*8);
            *(h8_t*)&BL_i[tid][c*8] = *(const h8_t*)(si + c*8);
        }
    }
    __syncthreads();

    f4_t accr[4][4], acci[4][4];
    #pragma unroll
    for (int m = 0; m < 4; ++m)
        #pragma unroll
        for (int t = 0; t < 4; ++t) {
            accr[m][t] = (f4_t){0.f,0.f,0.f,0.f};
            acci[m][t] = (f4_t){0.f,0.f,0.f,0.f};
        }

    // ---- K loop: 8 slabs of 32 ----
    for (int ks = 0; ks < 8; ++ks) {
        h8_t Ar[4], Ai[4];
        #pragma unroll
        for (int m = 0; m < 4; ++m) {
            Ar[m] = *(const h8_t*)&As_r[m*16 + col][ks*32 + lg*8];
            Ai[m] = *(const h8_t*)&As_i[m*16 + col][ks*32 + lg*8];
        }
        #pragma unroll
        for (int t = 0; t < 4; ++t) {
            const int n = (wv*4 + t) * 16 + col;
            h8_t Br  = *(const h8_t*)&BL_r[n][lg*8];
            h8_t Bi  = *(const h8_t*)&BL_i[n][lg*8];
            h8_t nBi = -Bi;
            #pragma unroll
            for (int m = 0; m < 4; ++m) {
                accr[m][t] = mfma16(Ar[m], Br,  accr[m][t]);
                accr[m][t] = mfma16(Ai[m], nBi, accr[m][t]);
                acci[m][t] = mfma16(Ar[m], Bi,  acci[m][t]);
                acci[m][t] = mfma16(Ai[m], Br,  acci[m][t]);
            }
        }
        __syncthreads();
        if (ks < 7) {
            const f16* sr = bt_r + tid * 256 + (ks+1) * 32;
            const f16* si = bt_i + tid * 256 + (ks+1) * 32;
            #pragma unroll
            for (int c = 0; c < 4; ++c) {
                *(h8_t*)&BL_r[tid][c*8] = *(const h8_t*)(sr + c*8);
                *(h8_t*)&BL_i[tid][c*8] = *(const h8_t*)(si + c*8);
            }
            __syncthreads();
        }
    }

    // ---- measurement: z_q = sum_i (-1)^{parity(i & R_q)} |phi_i|^2 ----
    // C/D layout (HW-verified): lane holds rows (lg*4+v), col = lane&15.
    // i = nt*16 + col  (high nibble nt, low nibble col).
    constexpr int RM8[8] = {0x80, 0x40, 0x20, 0x10, 0x88, 0x44, 0x22, 0x11};
    float sgl_[8];
    #pragma unroll
    for (int q = 0; q < 8; ++q)
        sgl_[q] = (__builtin_popcount(col & (RM8[q] & 15)) & 1) ? -1.f : 1.f;

    float z[4][4][8];
    #pragma unroll
    for (int m = 0; m < 4; ++m)
        #pragma unroll
        for (int v = 0; v < 4; ++v)
            #pragma unroll
            for (int q = 0; q < 8; ++q) z[m][v][q] = 0.f;

    #pragma unroll
    for (int t = 0; t < 4; ++t) {
        const int nt = wv*4 + t;
        float sgf[8];
        #pragma unroll
        for (int q = 0; q < 8; ++q)
            sgf[q] = (__builtin_popcount(nt & (RM8[q] >> 4)) & 1) ? -sgl_[q] : sgl_[q];
        #pragma unroll
        for (int m = 0; m < 4; ++m)
            #pragma unroll
            for (int v = 0; v < 4; ++v) {
                const float p = accr[m][t][v]*accr[m][t][v]
                              + acci[m][t][v]*acci[m][t][v];
                #pragma unroll
                for (int q = 0; q < 8; ++q)
                    z[m][v][q] = fmaf(sgf[q], p, z[m][v][q]);
            }
    }
    // reduce over the 16 cols (within 16-lane groups)
    #pragma unroll
    for (int m = 0; m < 4; ++m)
        #pragma unroll
        for (int v = 0; v < 4; ++v)
            #pragma unroll
            for (int q = 0; q < 8; ++q) {
                float r = z[m][v][q];
                r += shxm<1>(r); r += shxm<2>(r);
                r += shxm<4>(r); r += shxm<8>(r);
                z[m][v][q] = r;
            }
    // deposit per-wave partials (static q indexing; all 16 lanes hold the sum)
    #pragma unroll
    for (int q = 0; q < 8; ++q)
        if (col == q) {
            #pragma unroll
            for (int m = 0; m < 4; ++m)
                #pragma unroll
                for (int v = 0; v < 4; ++v)
                    zbuf[wv][m*16 + lg*4 + v][q] = z[m][v][q];
        }
    __syncthreads();
    // sum the 4 waves' nt-group partials and write out
    #pragma unroll
    for (int k = 0; k < 2; ++k) {
        const int slot = tid * 2 + k;
        const int s = slot >> 3, q = slot & 7;
        out[(blockIdx.x * 64 + s) * 8 + q] =
            zbuf[0][s][q] + zbuf[1][s][q] + zbuf[2][s][q] + zbuf[3][s][q];
    }
}

extern "C" void kernel_launch(void* const* d_in, const int* in_sizes, int n_in,
                              void* d_out, int out_size, void* d_ws, size_t ws_size,
                              hipStream_t stream) {
    const float* x = (const float*)d_in[0];
    const float* w = (const float*)d_in[1];
    float* out = (float*)d_out;
    const int B = in_sizes[0] / 8;                 // 16384 samples
    f16* bt_r = (f16*)d_ws;
    f16* bt_i = bt_r + 256 * 256;
    build_u<<<16, 256, 0, stream>>>(w, bt_r, bt_i);
    qsim_mm<<<(B + 63) / 64, 256, 0, stream>>>(x, w, bt_r, bt_i, out);
}

// Round 9
// 90.208 us; speedup vs baseline: 1.1409x; 1.1409x over previous
//
#include <hip/hip_runtime.h>

// 8-qubit statevector sim, R9: MFMA reformulation, scheduling fixed.
// phi = Utilde * psi; Utilde (256x256, weights-only) = layers 1-3 with CNOTs
// deferred (validated mask machinery); psi = encode+layer0 product state
// (validated R6 fold); measurement = signed sums, masks R={80,40,20,10,88,44,22,11}.
// R8 was correct but: 150KB LDS -> 1 blk/CU, 2 barriers/K-slab, 1.5M bank
// conflicts -> MfmaUtil 5%. R9:
//  * B read directly from global (L2-resident 256KB, shared by all blocks),
//    per-lane base + compile-time ks*64B offset -> K-loop has NO barriers.
//  * 32 samples/block x 512 threads -> grid 512, 2 blocks/CU, 4 waves/SIMD.
//  * psi LDS tile XOR-swizzled (chunk ^= (row&7)<<2) -> conflict-free.
//  * B double-buffered in registers; -Ai (2 negs/slab) instead of -Bi (4).
//  * epilogue: one butterfly per q gives z_q (plain col-sum) and z_{q+4}
//    (col-bit-signed sum) from shared partials.

typedef _Float16 f16;
typedef _Float16 h8_t __attribute__((ext_vector_type(8)));
typedef float f4_t __attribute__((ext_vector_type(4)));

#define NGATES 32

// ---------------- validated deferred-CNOT mask machinery ----------------
constexpr bool selon(int l, int d) {
    return (l == 0) ? (d == 0) : (((d + l - 1) & (l - 1)) == (l - 1));
}
constexpr int lm_of(int l, int q) {
    int m = 0;
    for (int d = 0; q + d <= 7; ++d)
        if ((l & d) == d) { int qq = q + d; if (qq <= 3) m |= 1 << (3 - qq); }
    return m;
}
constexpr int rm_of(int l, int q) {
    int m = 0;
    for (int d = 0; q + d <= 7; ++d)
        if ((l & d) == d) { int qq = q + d; if (qq >= 4) m |= 1 << (7 - qq); }
    return m;
}
constexpr int slm_of(int l, int q) {
    int m = 0;
    for (int d = 0; d <= q; ++d)
        if (selon(l, d)) { int k = q - d; if (k <= 3) m |= 1 << (3 - k); }
    return m;
}
constexpr int srm_of(int l, int q) {
    int m = 0;
    for (int d = 0; d <= q; ++d)
        if (selon(l, d)) { int k = q - d; if (k >= 4) m |= 1 << (7 - k); }
    return m;
}

__device__ __forceinline__ float xsgn(float f, unsigned m) {
    return __int_as_float(__float_as_int(f) ^ (int)m);
}

template<int C>
__device__ __forceinline__ int dppmov(int x) {
    return __builtin_amdgcn_update_dpp(x, x, C, 0xF, 0xF, false);
}
template<int M>
__device__ __forceinline__ float shx_dpp(float v) {
    int x = __float_as_int(v);
    if constexpr (M == 1)       { x = dppmov<0xB1>(x); }
    else if constexpr (M == 2)  { x = dppmov<0x4E>(x); }
    else if constexpr (M == 3)  { x = dppmov<0x1B>(x); }
    else if constexpr (M == 7)  { x = dppmov<0x141>(x); }
    else if constexpr (M == 8)  { x = dppmov<0x128>(x); }
    else                        { x = dppmov<0x140>(x); }  // 15
    return __int_as_float(x);
}
template<int M>
__device__ __forceinline__ float shx_ds(float v) {
    return __int_as_float(__builtin_amdgcn_ds_swizzle(__float_as_int(v), (M << 10) | 0x1F));
}
constexpr bool sgl(int M) {
    return M == 1 || M == 2 || M == 3 || M == 7 || M == 8 || M == 15;
}
template<int M>
__device__ __forceinline__ float shxm(float v) {
    if constexpr (sgl(M)) return shx_dpp<M>(v);
    else                  return shx_ds<M>(v);
}

template<int LM, int RM, int SLM, int SRM>
__device__ __forceinline__ void apply_gate(float ar[16], float ai[16], int lane,
                                           const float4 g)
{
    unsigned sm = 0;
    if constexpr (SLM != 0)
        sm = (unsigned)((__builtin_popcount(lane & SLM) & 1) << 31);
    const float c0r = g.x, c1i = g.w;
    const float c0i0 = xsgn(g.y, sm);
    const float c1r0 = xsgn(g.z, sm);
    const float c0i1 = xsgn(g.y, sm ^ 0x80000000u);
    const float c1r1 = xsgn(g.z, sm ^ 0x80000000u);

    float br[16], bi[16];
    #pragma unroll
    for (int r = 0; r < 16; ++r) {
        float pr = ar[r ^ RM], pi = ai[r ^ RM];
        if constexpr (LM != 0) { pr = shxm<LM>(pr); pi = shxm<LM>(pi); }
        br[r] = pr; bi[r] = pi;
    }
    #pragma unroll
    for (int r = 0; r < 16; ++r) {
        const bool c1 = (__builtin_popcount(r & SRM) & 1) != 0;
        const float c0i = c1 ? c0i1 : c0i0;
        const float c1r = c1 ? c1r1 : c1r0;
        const float nr = c0r*ar[r] - c0i*ai[r] + c1r*br[r] - c1i*bi[r];
        const float ni = c0r*ai[r] + c0i*ar[r] + c1r*bi[r] + c1i*br[r];
        ar[r] = nr; ai[r] = ni;
    }
}

#define GATE(L, Q) apply_gate<lm_of(L,Q), rm_of(L,Q), slm_of(L,Q), srm_of(L,Q)>( \
                       ar, ai, lane, gsh4[(L)*8+(Q)])
#define LAYER(L) GATE(L,0); GATE(L,1); GATE(L,2); GATE(L,3); \
                 GATE(L,4); GATE(L,5); GATE(L,6); GATE(L,7);

// fused U = RZ*RY*RX row0 (u11=conj(u00), u10=-conj(u01))
__device__ __forceinline__ float4 gate_row0(const float* w, int g) {
    float hx = 0.5f * w[g*3+0];
    float hy = 0.5f * w[g*3+1];
    float hz = 0.5f * w[g*3+2];
    float cx = cosf(hx), sx = sinf(hx);
    float cy = cosf(hy), sy = sinf(hy);
    float cz = cosf(hz), sz = sinf(hz);
    float m00r = cy*cx,  m00i =  sy*sx;
    float m01r = -sy*cx, m01i = -cy*sx;
    return make_float4(cz*m00r + sz*m00i,
                       cz*m00i - sz*m00r,
                       cz*m01r + sz*m01i,
                       cz*m01i - sz*m01r);
}

// ---------------- kernel A: build Utilde columns (validated R8) ----------------
__global__ __launch_bounds__(256, 4) void build_u(const float* __restrict__ w,
                                                  f16* __restrict__ bt_r,
                                                  f16* __restrict__ bt_i)
{
    __shared__ float4 gsh4[NGATES];
    const int tid = threadIdx.x;
    if (tid < NGATES) gsh4[tid] = gate_row0(w, tid);
    __syncthreads();

    const int lane = tid & 63;
    const int il   = lane & 15;
    const int j    = blockIdx.x * 16 + (tid >> 4);   // basis index 0..255

    float ar[16], ai[16];
    #pragma unroll
    for (int r = 0; r < 16; ++r) {
        ar[r] = (il == (j >> 4) && r == (j & 15)) ? 1.f : 0.f;
        ai[r] = 0.f;
    }
    LAYER(1)
    LAYER(2)
    LAYER(3)
    #pragma unroll
    for (int r = 0; r < 16; ++r) {
        const int i = il * 16 + r;
        bt_r[i * 256 + j] = (f16)ar[r];
        bt_i[i * 256 + j] = (f16)ai[r];
    }
}

// ---------------- kernel B: encode + GEMM + measurement ----------------
struct cpx { float r, i; };
__device__ __forceinline__ cpx cmul(cpx a, cpx b) {
    return { a.r*b.r - a.i*b.i, a.r*b.i + a.i*b.r };
}
__device__ __forceinline__ f4_t mfma16(h8_t a, h8_t b, f4_t c) {
    return __builtin_amdgcn_mfma_f32_16x16x32_f16(a, b, c, 0, 0, 0);
}

// col-group butterfly: returns S = sum over 16 cols, D = r - shx<BM>(r) partial
template<int BM>
__device__ __forceinline__ void colreduce(float A, float& S, float& D) {
    if constexpr (BM != 1) A += shxm<1>(A);
    if constexpr (BM != 2) A += shxm<2>(A);
    if constexpr (BM != 4) A += shxm<4>(A);
    if constexpr (BM != 8) A += shxm<8>(A);
    const float tb = shxm<BM>(A);
    S = A + tb;
    D = A - tb;
}

__global__ __launch_bounds__(512, 4) void qsim_mm(const float* __restrict__ x,
                                                  const float* __restrict__ w,
                                                  const f16* __restrict__ bt_r,
                                                  const f16* __restrict__ bt_i,
                                                  float* __restrict__ out)
{
    __shared__ f16   As2[2 * 32 * 256];   // [r/i][32 samples][256 k], swizzled
    __shared__ float zbuf[8][32][8];
    __shared__ float4 g0[8];

    const int tid  = threadIdx.x;
    const int lane = tid & 63;
    const int wv   = tid >> 6;          // wave 0..7 -> ntiles wv*2, wv*2+1
    const int lg   = lane >> 4;         // k-group / row-group 0..3
    const int col  = lane & 15;

    if (tid < 8) g0[tid] = gate_row0(w, tid);
    __syncthreads();

    // ---- encode: 32 samples x 16 threads; psi -> swizzled LDS (f16) ----
    {
        const int s  = tid >> 4;        // sample 0..31
        const int pt = tid & 15;        // k-chunk owner: amps pt*16..pt*16+15
        const float4* xp = (const float4*)(x + (blockIdx.x * 32 + s) * 8);
        float4 xa = xp[0], xb = xp[1];
        float xs[8] = {xa.x, xa.y, xa.z, xa.w, xb.x, xb.y, xb.z, xb.w};
        cpx f0[8], f1[8];
        #pragma unroll
        for (int q = 0; q < 8; ++q) {
            float c, s_;
            __sincosf(0.5f * xs[q], &s_, &c);
            const float4 g = g0[q];
            f0[q] = { g.x*c + g.z*s_, g.y*c + g.w*s_ };   // alpha
            f1[q] = { g.x*s_ - g.z*c, g.w*c - g.y*s_ };   // beta
        }
        cpx t01[4], t23[4], t45[4], t67[4];
        #pragma unroll
        for (int a = 0; a < 2; ++a)
            #pragma unroll
            for (int b = 0; b < 2; ++b) {
                t01[a*2+b] = cmul(a ? f1[0] : f0[0], b ? f1[1] : f0[1]);
                t23[a*2+b] = cmul(a ? f1[2] : f0[2], b ? f1[3] : f0[3]);
                t45[a*2+b] = cmul(a ? f1[4] : f0[4], b ? f1[5] : f0[5]);
                t67[a*2+b] = cmul(a ? f1[6] : f0[6], b ? f1[7] : f0[7]);
            }
        cpx P47[16];
        #pragma unroll
        for (int h = 0; h < 16; ++h) P47[h] = cmul(t45[h >> 2], t67[h & 3]);
        const cpx p03 = cmul(t01[pt >> 2], t23[pt & 3]);

        #pragma unroll
        for (int u = 0; u < 2; ++u) {
            h8_t vr, vi;
            #pragma unroll
            for (int e = 0; e < 8; ++e) {
                cpx cc = cmul(p03, P47[u*8 + e]);
                vr[e] = (f16)cc.r; vi[e] = (f16)cc.i;
            }
            const int cch = (2*pt + u) ^ ((s & 7) << 2);   // swizzled 16B chunk
            const int idx = s * 256 + cch * 8;
            *(h8_t*)&As2[idx]        = vr;
            *(h8_t*)&As2[idx + 8192] = vi;
        }
    }
    __syncthreads();

    // ---- barrier-free K loop: B direct from global, double-buffered regs ----
    const int n0 = wv * 32 + col;                  // ntile wv*2, row n0
    const f16* pr0 = bt_r + n0 * 256 + lg * 8;
    const f16* pi0 = bt_i + n0 * 256 + lg * 8;
    const f16* pr1 = pr0 + 16 * 256;               // ntile wv*2+1
    const f16* pi1 = pi0 + 16 * 256;

    const int cs = col & 7;
    const int ab0 = (0*16 + col) * 256 + lg * 8;   // m=0 row base (f16 idx)
    const int ab1 = (1*16 + col) * 256 + lg * 8;   // m=1 row base

    f4_t accr[2][2], acci[2][2];
    #pragma unroll
    for (int m = 0; m < 2; ++m)
        #pragma unroll
        for (int t = 0; t < 2; ++t) {
            accr[m][t] = (f4_t){0.f,0.f,0.f,0.f};
            acci[m][t] = (f4_t){0.f,0.f,0.f,0.f};
        }

    h8_t Br[2][2], Bi[2][2];                       // [buf][t]
    Br[0][0] = *(const h8_t*)(pr0);
    Bi[0][0] = *(const h8_t*)(pi0);
    Br[0][1] = *(const h8_t*)(pr1);
    Bi[0][1] = *(const h8_t*)(pi1);

    #pragma unroll
    for (int ks = 0; ks < 8; ++ks) {
        const int b = ks & 1;
        if (ks < 7) {
            const int kn = (ks + 1) * 32;
            Br[b^1][0] = *(const h8_t*)(pr0 + kn);
            Bi[b^1][0] = *(const h8_t*)(pi0 + kn);
            Br[b^1][1] = *(const h8_t*)(pr1 + kn);
            Bi[b^1][1] = *(const h8_t*)(pi1 + kn);
        }
        const int ko = ((ks ^ cs) << 5);           // swizzled k offset (f16)
        h8_t Ar0 = *(const h8_t*)&As2[ab0 + ko];
        h8_t Ai0 = *(const h8_t*)&As2[ab0 + ko + 8192];
        h8_t Ar1 = *(const h8_t*)&As2[ab1 + ko];
        h8_t Ai1 = *(const h8_t*)&As2[ab1 + ko + 8192];
        h8_t nAi0 = -Ai0, nAi1 = -Ai1;
        #pragma unroll
        for (int t = 0; t < 2; ++t) {
            accr[0][t] = mfma16(Ar0,  Br[b][t], accr[0][t]);
            accr[0][t] = mfma16(nAi0, Bi[b][t], accr[0][t]);
            acci[0][t] = mfma16(Ar0,  Bi[b][t], acci[0][t]);
            acci[0][t] = mfma16(Ai0,  Br[b][t], acci[0][t]);
            accr[1][t] = mfma16(Ar1,  Br[b][t], accr[1][t]);
            accr[1][t] = mfma16(nAi1, Bi[b][t], accr[1][t]);
            acci[1][t] = mfma16(Ar1,  Bi[b][t], acci[1][t]);
            acci[1][t] = mfma16(Ai1,  Br[b][t], acci[1][t]);
        }
    }

    // ---- measurement ----
    // C/D layout (HW-verified): lane holds col = lane&15 (= output i low nibble),
    // rows lg*4+v (= sample within m-tile). i = nt*16 + col, nt = wv*2+t.
    // q0-3: sign = parity(nt & (8>>q));  q4-7: same nt bit AND col bit (8>>q).
    float p[2][2][4];
    #pragma unroll
    for (int m = 0; m < 2; ++m)
        #pragma unroll
        for (int t = 0; t < 2; ++t)
            #pragma unroll
            for (int v = 0; v < 4; ++v)
                p[m][t][v] = accr[m][t][v]*accr[m][t][v]
                           + acci[m][t][v]*acci[m][t][v];

    #pragma unroll
    for (int q = 0; q < 4; ++q) {
        const int bm = 8 >> q;
        const unsigned s0 = ((wv*2 + 0) & bm) ? 0x80000000u : 0u;
        const unsigned s1 = ((wv*2 + 1) & bm) ? 0x80000000u : 0u;
        const unsigned cf = (col & bm) ? 0x80000000u : 0u;
        #pragma unroll
        for (int m = 0; m < 2; ++m)
            #pragma unroll
            for (int v = 0; v < 4; ++v) {
                float A = xsgn(p[m][0][v], s0) + xsgn(p[m][1][v], s1);
                float S, D;
                if      (q == 0) colreduce<8>(A, S, D);
                else if (q == 1) colreduce<4>(A, S, D);
                else if (q == 2) colreduce<2>(A, S, D);
                else             colreduce<1>(A, S, D);
                const float T = xsgn(D, cf);
                if (col == 0) {
                    zbuf[wv][m*16 + lg*4 + v][q]     = S;
                    zbuf[wv][m*16 + lg*4 + v][q + 4] = T;
                }
            }
    }
    __syncthreads();

    if (tid < 256) {
        const int s = tid >> 3, q = tid & 7;
        float acc = zbuf[0][s][q];
        #pragma unroll
        for (int wv2 = 1; wv2 < 8; ++wv2) acc += zbuf[wv2][s][q];
        out[(blockIdx.x * 32 + s) * 8 + q] = acc;
    }
}

extern "C" void kernel_launch(void* const* d_in, const int* in_sizes, int n_in,
                              void* d_out, int out_size, void* d_ws, size_t ws_size,
                              hipStream_t stream) {
    const float* x = (const float*)d_in[0];
    const float* w = (const float*)d_in[1];
    float* out = (float*)d_out;
    const int B = in_sizes[0] / 8;                 // 16384 samples
    f16* bt_r = (f16*)d_ws;
    f16* bt_i = bt_r + 256 * 256;
    build_u<<<16, 256, 0, stream>>>(w, bt_r, bt_i);
    qsim_mm<<<(B + 31) / 32, 512, 0, stream>>>(x, w, bt_r, bt_i, out);
}

// Round 10
// 90.077 us; speedup vs baseline: 1.1426x; 1.0015x over previous
//
#include <hip/hip_runtime.h>

// 8-qubit statevector sim, R10: MFMA reformulation, spill + bank-conflict fix.
// phi = Utilde * psi; Utilde (256x256, weights-only) = layers 1-3 with CNOTs
// deferred (validated mask machinery); psi = encode+layer0 product state
// (validated R6 fold); measurement = signed sums, masks R={80,40,20,10,88,44,22,11}.
// R9 (~40us qsim_mm): __launch_bounds__(512,4) capped VGPR at 128 while encode
// holds ~100 live floats and the K-loop ~120 -> scratch spills in the hot loop
// (~900cyc each). Also the A-tile swizzle was 64B-granular -> only 2 bank
// phases -> 8-way conflict on every A ds_read_b128.
// R10 (minimal diff from R9):
//  * __launch_bounds__(512, 2): VGPR cap 256, no spills; 2 blocks/CU via LDS.
//  * 16B-granule XOR swizzle (chunk ^= row&7, write AND read) -> 2-way = free.
//  * everything else identical (barrier-free K loop, B from L2, reg dbuf).

typedef _Float16 f16;
typedef _Float16 h8_t __attribute__((ext_vector_type(8)));
typedef float f4_t __attribute__((ext_vector_type(4)));

#define NGATES 32

// ---------------- validated deferred-CNOT mask machinery ----------------
constexpr bool selon(int l, int d) {
    return (l == 0) ? (d == 0) : (((d + l - 1) & (l - 1)) == (l - 1));
}
constexpr int lm_of(int l, int q) {
    int m = 0;
    for (int d = 0; q + d <= 7; ++d)
        if ((l & d) == d) { int qq = q + d; if (qq <= 3) m |= 1 << (3 - qq); }
    return m;
}
constexpr int rm_of(int l, int q) {
    int m = 0;
    for (int d = 0; q + d <= 7; ++d)
        if ((l & d) == d) { int qq = q + d; if (qq >= 4) m |= 1 << (7 - qq); }
    return m;
}
constexpr int slm_of(int l, int q) {
    int m = 0;
    for (int d = 0; d <= q; ++d)
        if (selon(l, d)) { int k = q - d; if (k <= 3) m |= 1 << (3 - k); }
    return m;
}
constexpr int srm_of(int l, int q) {
    int m = 0;
    for (int d = 0; d <= q; ++d)
        if (selon(l, d)) { int k = q - d; if (k >= 4) m |= 1 << (7 - k); }
    return m;
}

__device__ __forceinline__ float xsgn(float f, unsigned m) {
    return __int_as_float(__float_as_int(f) ^ (int)m);
}

template<int C>
__device__ __forceinline__ int dppmov(int x) {
    return __builtin_amdgcn_update_dpp(x, x, C, 0xF, 0xF, false);
}
template<int M>
__device__ __forceinline__ float shx_dpp(float v) {
    int x = __float_as_int(v);
    if constexpr (M == 1)       { x = dppmov<0xB1>(x); }
    else if constexpr (M == 2)  { x = dppmov<0x4E>(x); }
    else if constexpr (M == 3)  { x = dppmov<0x1B>(x); }
    else if constexpr (M == 7)  { x = dppmov<0x141>(x); }
    else if constexpr (M == 8)  { x = dppmov<0x128>(x); }
    else                        { x = dppmov<0x140>(x); }  // 15
    return __int_as_float(x);
}
template<int M>
__device__ __forceinline__ float shx_ds(float v) {
    return __int_as_float(__builtin_amdgcn_ds_swizzle(__float_as_int(v), (M << 10) | 0x1F));
}
constexpr bool sgl(int M) {
    return M == 1 || M == 2 || M == 3 || M == 7 || M == 8 || M == 15;
}
template<int M>
__device__ __forceinline__ float shxm(float v) {
    if constexpr (sgl(M)) return shx_dpp<M>(v);
    else                  return shx_ds<M>(v);
}

template<int LM, int RM, int SLM, int SRM>
__device__ __forceinline__ void apply_gate(float ar[16], float ai[16], int lane,
                                           const float4 g)
{
    unsigned sm = 0;
    if constexpr (SLM != 0)
        sm = (unsigned)((__builtin_popcount(lane & SLM) & 1) << 31);
    const float c0r = g.x, c1i = g.w;
    const float c0i0 = xsgn(g.y, sm);
    const float c1r0 = xsgn(g.z, sm);
    const float c0i1 = xsgn(g.y, sm ^ 0x80000000u);
    const float c1r1 = xsgn(g.z, sm ^ 0x80000000u);

    float br[16], bi[16];
    #pragma unroll
    for (int r = 0; r < 16; ++r) {
        float pr = ar[r ^ RM], pi = ai[r ^ RM];
        if constexpr (LM != 0) { pr = shxm<LM>(pr); pi = shxm<LM>(pi); }
        br[r] = pr; bi[r] = pi;
    }
    #pragma unroll
    for (int r = 0; r < 16; ++r) {
        const bool c1 = (__builtin_popcount(r & SRM) & 1) != 0;
        const float c0i = c1 ? c0i1 : c0i0;
        const float c1r = c1 ? c1r1 : c1r0;
        const float nr = c0r*ar[r] - c0i*ai[r] + c1r*br[r] - c1i*bi[r];
        const float ni = c0r*ai[r] + c0i*ar[r] + c1r*bi[r] + c1i*br[r];
        ar[r] = nr; ai[r] = ni;
    }
}

#define GATE(L, Q) apply_gate<lm_of(L,Q), rm_of(L,Q), slm_of(L,Q), srm_of(L,Q)>( \
                       ar, ai, lane, gsh4[(L)*8+(Q)])
#define LAYER(L) GATE(L,0); GATE(L,1); GATE(L,2); GATE(L,3); \
                 GATE(L,4); GATE(L,5); GATE(L,6); GATE(L,7);

// fused U = RZ*RY*RX row0 (u11=conj(u00), u10=-conj(u01))
__device__ __forceinline__ float4 gate_row0(const float* w, int g) {
    float hx = 0.5f * w[g*3+0];
    float hy = 0.5f * w[g*3+1];
    float hz = 0.5f * w[g*3+2];
    float cx = cosf(hx), sx = sinf(hx);
    float cy = cosf(hy), sy = sinf(hy);
    float cz = cosf(hz), sz = sinf(hz);
    float m00r = cy*cx,  m00i =  sy*sx;
    float m01r = -sy*cx, m01i = -cy*sx;
    return make_float4(cz*m00r + sz*m00i,
                       cz*m00i - sz*m00r,
                       cz*m01r + sz*m01i,
                       cz*m01i - sz*m01r);
}

// ---------------- kernel A: build Utilde columns (validated R8/R9) ----------------
__global__ __launch_bounds__(256, 4) void build_u(const float* __restrict__ w,
                                                  f16* __restrict__ bt_r,
                                                  f16* __restrict__ bt_i)
{
    __shared__ float4 gsh4[NGATES];
    const int tid = threadIdx.x;
    if (tid < NGATES) gsh4[tid] = gate_row0(w, tid);
    __syncthreads();

    const int lane = tid & 63;
    const int il   = lane & 15;
    const int j    = blockIdx.x * 16 + (tid >> 4);   // basis index 0..255

    float ar[16], ai[16];
    #pragma unroll
    for (int r = 0; r < 16; ++r) {
        ar[r] = (il == (j >> 4) && r == (j & 15)) ? 1.f : 0.f;
        ai[r] = 0.f;
    }
    LAYER(1)
    LAYER(2)
    LAYER(3)
    #pragma unroll
    for (int r = 0; r < 16; ++r) {
        const int i = il * 16 + r;
        bt_r[i * 256 + j] = (f16)ar[r];
        bt_i[i * 256 + j] = (f16)ai[r];
    }
}

// ---------------- kernel B: encode + GEMM + measurement ----------------
struct cpx { float r, i; };
__device__ __forceinline__ cpx cmul(cpx a, cpx b) {
    return { a.r*b.r - a.i*b.i, a.r*b.i + a.i*b.r };
}
__device__ __forceinline__ f4_t mfma16(h8_t a, h8_t b, f4_t c) {
    return __builtin_amdgcn_mfma_f32_16x16x32_f16(a, b, c, 0, 0, 0);
}

// col-group butterfly: S = sum over 16 cols, D = bit-BM-signed partial
template<int BM>
__device__ __forceinline__ void colreduce(float A, float& S, float& D) {
    if constexpr (BM != 1) A += shxm<1>(A);
    if constexpr (BM != 2) A += shxm<2>(A);
    if constexpr (BM != 4) A += shxm<4>(A);
    if constexpr (BM != 8) A += shxm<8>(A);
    const float tb = shxm<BM>(A);
    S = A + tb;
    D = A - tb;
}

__global__ __launch_bounds__(512, 2) void qsim_mm(const float* __restrict__ x,
                                                  const float* __restrict__ w,
                                                  const f16* __restrict__ bt_r,
                                                  const f16* __restrict__ bt_i,
                                                  float* __restrict__ out)
{
    __shared__ f16   As2[2 * 32 * 256];   // [r/i][32 samples][256 k], 16B-swizzled
    __shared__ float zbuf[8][32][8];
    __shared__ float4 g0[8];

    const int tid  = threadIdx.x;
    const int lane = tid & 63;
    const int wv   = tid >> 6;          // wave 0..7 -> ntiles wv*2, wv*2+1
    const int lg   = lane >> 4;         // k-group / row-group 0..3
    const int col  = lane & 15;

    if (tid < 8) g0[tid] = gate_row0(w, tid);
    __syncthreads();

    // ---- encode: 32 samples x 16 threads; psi -> swizzled LDS (f16) ----
    {
        const int s  = tid >> 4;        // sample 0..31
        const int pt = tid & 15;        // owns 16B chunks 2pt, 2pt+1
        const float4* xp = (const float4*)(x + (blockIdx.x * 32 + s) * 8);
        float4 xa = xp[0], xb = xp[1];
        float xs[8] = {xa.x, xa.y, xa.z, xa.w, xb.x, xb.y, xb.z, xb.w};
        cpx f0[8], f1[8];
        #pragma unroll
        for (int q = 0; q < 8; ++q) {
            float c, s_;
            __sincosf(0.5f * xs[q], &s_, &c);
            const float4 g = g0[q];
            f0[q] = { g.x*c + g.z*s_, g.y*c + g.w*s_ };   // alpha
            f1[q] = { g.x*s_ - g.z*c, g.w*c - g.y*s_ };   // beta
        }
        cpx t01[4], t23[4], t45[4], t67[4];
        #pragma unroll
        for (int a = 0; a < 2; ++a)
            #pragma unroll
            for (int b = 0; b < 2; ++b) {
                t01[a*2+b] = cmul(a ? f1[0] : f0[0], b ? f1[1] : f0[1]);
                t23[a*2+b] = cmul(a ? f1[2] : f0[2], b ? f1[3] : f0[3]);
                t45[a*2+b] = cmul(a ? f1[4] : f0[4], b ? f1[5] : f0[5]);
                t67[a*2+b] = cmul(a ? f1[6] : f0[6], b ? f1[7] : f0[7]);
            }
        cpx P47[16];
        #pragma unroll
        for (int h = 0; h < 16; ++h) P47[h] = cmul(t45[h >> 2], t67[h & 3]);
        const cpx p03 = cmul(t01[pt >> 2], t23[pt & 3]);

        #pragma unroll
        for (int u = 0; u < 2; ++u) {
            h8_t vr, vi;
            #pragma unroll
            for (int e = 0; e < 8; ++e) {
                cpx cc = cmul(p03, P47[u*8 + e]);
                vr[e] = (f16)cc.r; vi[e] = (f16)cc.i;
            }
            const int cch = (2*pt + u) ^ (s & 7);          // 16B-granule swizzle
            const int idx = s * 256 + cch * 8;
            *(h8_t*)&As2[idx]        = vr;
            *(h8_t*)&As2[idx + 8192] = vi;
        }
    }
    __syncthreads();

    // ---- barrier-free K loop: B direct from global, double-buffered regs ----
    const int n0 = wv * 32 + col;                  // ntile 2wv, row n0
    const f16* pr0 = bt_r + n0 * 256 + lg * 8;
    const f16* pi0 = bt_i + n0 * 256 + lg * 8;
    const f16* pr1 = pr0 + 16 * 256;               // ntile 2wv+1
    const f16* pi1 = pi0 + 16 * 256;

    const int cs  = col & 7;                       // row&7 for both m-tiles
    const int ab0 = (0*16 + col) * 256;            // m=0 row base (f16 idx)
    const int ab1 = (1*16 + col) * 256;            // m=1 row base

    f4_t accr[2][2], acci[2][2];
    #pragma unroll
    for (int m = 0; m < 2; ++m)
        #pragma unroll
        for (int t = 0; t < 2; ++t) {
            accr[m][t] = (f4_t){0.f,0.f,0.f,0.f};
            acci[m][t] = (f4_t){0.f,0.f,0.f,0.f};
        }

    h8_t Br[2][2], Bi[2][2];                       // [buf][t]
    Br[0][0] = *(const h8_t*)(pr0);
    Bi[0][0] = *(const h8_t*)(pi0);
    Br[0][1] = *(const h8_t*)(pr1);
    Bi[0][1] = *(const h8_t*)(pi1);

    #pragma unroll
    for (int ks = 0; ks < 8; ++ks) {
        const int b = ks & 1;
        if (ks < 7) {
            const int kn = (ks + 1) * 32;
            Br[b^1][0] = *(const h8_t*)(pr0 + kn);
            Bi[b^1][0] = *(const h8_t*)(pi0 + kn);
            Br[b^1][1] = *(const h8_t*)(pr1 + kn);
            Bi[b^1][1] = *(const h8_t*)(pi1 + kn);
        }
        // A chunk for slab ks, k-group lg, row r: chunk' = (ks*4+lg)^(r&7)
        const int ko = (((ks << 2) | lg) ^ cs) << 3;
        h8_t Ar0 = *(const h8_t*)&As2[ab0 + ko];
        h8_t Ai0 = *(const h8_t*)&As2[ab0 + ko + 8192];
        h8_t Ar1 = *(const h8_t*)&As2[ab1 + ko];
        h8_t Ai1 = *(const h8_t*)&As2[ab1 + ko + 8192];
        h8_t nAi0 = -Ai0, nAi1 = -Ai1;
        #pragma unroll
        for (int t = 0; t < 2; ++t) {
            accr[0][t] = mfma16(Ar0,  Br[b][t], accr[0][t]);
            accr[0][t] = mfma16(nAi0, Bi[b][t], accr[0][t]);
            acci[0][t] = mfma16(Ar0,  Bi[b][t], acci[0][t]);
            acci[0][t] = mfma16(Ai0,  Br[b][t], acci[0][t]);
            accr[1][t] = mfma16(Ar1,  Br[b][t], accr[1][t]);
            accr[1][t] = mfma16(nAi1, Bi[b][t], accr[1][t]);
            acci[1][t] = mfma16(Ar1,  Bi[b][t], acci[1][t]);
            acci[1][t] = mfma16(Ai1,  Br[b][t], acci[1][t]);
        }
    }

    // ---- measurement ----
    // C/D layout (HW-verified): lane holds col = lane&15 (= output i low nibble),
    // rows lg*4+v (= sample within m-tile). i = nt*16 + col, nt = 2wv+t.
    // q0-3: sign = parity(nt & (8>>q));  q4-7: same nt bit AND col bit (8>>q).
    float p[2][2][4];
    #pragma unroll
    for (int m = 0; m < 2; ++m)
        #pragma unroll
        for (int t = 0; t < 2; ++t)
            #pragma unroll
            for (int v = 0; v < 4; ++v)
                p[m][t][v] = accr[m][t][v]*accr[m][t][v]
                           + acci[m][t][v]*acci[m][t][v];

    #pragma unroll
    for (int q = 0; q < 4; ++q) {
        const int bm = 8 >> q;
        const unsigned s0 = ((wv*2 + 0) & bm) ? 0x80000000u : 0u;
        const unsigned s1 = ((wv*2 + 1) & bm) ? 0x80000000u : 0u;
        const unsigned cf = (col & bm) ? 0x80000000u : 0u;
        #pragma unroll
        for (int m = 0; m < 2; ++m)
            #pragma unroll
            for (int v = 0; v < 4; ++v) {
                float A = xsgn(p[m][0][v], s0) + xsgn(p[m][1][v], s1);
                float S, D;
                if      (q == 0) colreduce<8>(A, S, D);
                else if (q == 1) colreduce<4>(A, S, D);
                else if (q == 2) colreduce<2>(A, S, D);
                else             colreduce<1>(A, S, D);
                const float T = xsgn(D, cf);
                if (col == 0) {
                    zbuf[wv][m*16 + lg*4 + v][q]     = S;
                    zbuf[wv][m*16 + lg*4 + v][q + 4] = T;
                }
            }
    }
    __syncthreads();

    if (tid < 256) {
        const int s = tid >> 3, q = tid & 7;
        float acc = zbuf[0][s][q];
        #pragma unroll
        for (int wv2 = 1; wv2 < 8; ++wv2) acc += zbuf[wv2][s][q];
        out[(blockIdx.x * 32 + s) * 8 + q] = acc;
    }
}

extern "C" void kernel_launch(void* const* d_in, const int* in_sizes, int n_in,
                              void* d_out, int out_size, void* d_ws, size_t ws_size,
                              hipStream_t stream) {
    const float* x = (const float*)d_in[0];
    const float* w = (const float*)d_in[1];
    float* out = (float*)d_out;
    const int B = in_sizes[0] / 8;                 // 16384 samples
    f16* bt_r = (f16*)d_ws;
    f16* bt_i = bt_r + 256 * 256;
    build_u<<<16, 256, 0, stream>>>(w, bt_r, bt_i);
    qsim_mm<<<(B + 31) / 32, 512, 0, stream>>>(x, w, bt_r, bt_i, out);
}